// Round 1
// baseline (620.678 us; speedup 1.0000x reference)
//
#include <hip/hip_runtime.h>
#include <math.h>

#define N_NODES 100000
#define N_EDGES 3200000

// ---------------- workspace layout (floats) ----------------
// deg    : [0,        N)        weighted in-degree incl. self loop
// dinv   : [N,       2N)        rsqrt(deg)
// h1     : [2N,     18N)        x @ W1                [N,16]
// agg1   : [18N,    34N)        scatter accumulator   [N,16]
// h2     : [34N,    50N)        relu(conv1 out)       [N,16]
// x2pre  : [50N,    52N)        h2 @ W2               [N,2]
// agg2   : [52N,    54N)        scatter accumulator   [N,2]

__global__ void init_deg(float* __restrict__ deg) {
    int i = blockIdx.x * blockDim.x + threadIdx.x;
    if (i < N_NODES) deg[i] = 1.0f;  // self-loop weight = 1
}

__global__ void deg_accum(const int* __restrict__ dst, const float* __restrict__ w,
                          float* __restrict__ deg) {
    int e = blockIdx.x * blockDim.x + threadIdx.x;
    if (e < N_EDGES) atomicAdd(&deg[dst[e]], w[e]);
}

__global__ void deg_rsqrt(const float* __restrict__ deg, float* __restrict__ dinv) {
    int i = blockIdx.x * blockDim.x + threadIdx.x;
    if (i < N_NODES) {
        float d = deg[i];
        dinv[i] = d > 0.0f ? rsqrtf(d) : 0.0f;
    }
}

// h1 = x @ W1   ([N,64] @ [64,16]); 16 threads per node, one per out feature
__global__ void gemm1(const float* __restrict__ x, const float* __restrict__ W1,
                      float* __restrict__ h1) {
    __shared__ float sW[64 * 16];
    for (int t = threadIdx.x; t < 64 * 16; t += blockDim.x) sW[t] = W1[t];
    __syncthreads();
    int gid = blockIdx.x * blockDim.x + threadIdx.x;
    int node = gid >> 4, c = gid & 15;
    if (node >= N_NODES) return;
    const float* xr = x + node * 64;
    float acc = 0.0f;
#pragma unroll
    for (int k = 0; k < 64; k++) acc += xr[k] * sW[k * 16 + c];
    h1[node * 16 + c] = acc;
}

// conv1 message scatter: 16 lanes per edge, one per feature
__global__ void scatter1(const int* __restrict__ src, const int* __restrict__ dst,
                         const float* __restrict__ w, const float* __restrict__ dinv,
                         const float* __restrict__ h1, float* __restrict__ agg1) {
    int gid = blockIdx.x * blockDim.x + threadIdx.x;
    int e = gid >> 4, c = gid & 15;
    if (e >= N_EDGES) return;
    int s = src[e], d = dst[e];
    float nrm = dinv[s] * w[e] * dinv[d];
    atomicAdd(&agg1[d * 16 + c], h1[s * 16 + c] * nrm);
}

// h2 = relu(agg1 + self-loop + b1)
__global__ void post1(const float* __restrict__ agg1, const float* __restrict__ h1,
                      const float* __restrict__ dinv, const float* __restrict__ b1,
                      float* __restrict__ h2) {
    int gid = blockIdx.x * blockDim.x + threadIdx.x;
    int i = gid >> 4, c = gid & 15;
    if (i >= N_NODES) return;
    float di = dinv[i];
    float v = agg1[i * 16 + c] + h1[i * 16 + c] * di * di + b1[c];
    h2[i * 16 + c] = v > 0.0f ? v : 0.0f;
}

// x2pre = h2 @ W2   ([N,16] @ [16,2]); one thread per node
__global__ void gemm2(const float* __restrict__ h2, const float* __restrict__ W2,
                      float* __restrict__ x2pre) {
    __shared__ float sW[32];
    if (threadIdx.x < 32) sW[threadIdx.x] = W2[threadIdx.x];
    __syncthreads();
    int i = blockIdx.x * blockDim.x + threadIdx.x;
    if (i >= N_NODES) return;
    float a0 = 0.0f, a1 = 0.0f;
#pragma unroll
    for (int c = 0; c < 16; c++) {
        float v = h2[i * 16 + c];
        a0 += v * sW[c * 2];
        a1 += v * sW[c * 2 + 1];
    }
    x2pre[i * 2] = a0;
    x2pre[i * 2 + 1] = a1;
}

// conv2 message scatter: 2 lanes per edge
__global__ void scatter2(const int* __restrict__ src, const int* __restrict__ dst,
                         const float* __restrict__ w, const float* __restrict__ dinv,
                         const float* __restrict__ x2pre, float* __restrict__ agg2) {
    int gid = blockIdx.x * blockDim.x + threadIdx.x;
    int e = gid >> 1, d = gid & 1;
    if (e >= N_EDGES) return;
    int s = src[e], t = dst[e];
    float nrm = dinv[s] * w[e] * dinv[t];
    atomicAdd(&agg2[t * 2 + d], x2pre[s * 2 + d] * nrm);
}

// x2 = agg2 + self-loop + b2 ; out = sigmoid(relu(x2) @ lin_w + lin_b)
__global__ void final_k(const float* __restrict__ agg2, const float* __restrict__ x2pre,
                        const float* __restrict__ dinv, const float* __restrict__ b2,
                        const float* __restrict__ lin_w, const float* __restrict__ lin_b,
                        float* __restrict__ out) {
    int i = blockIdx.x * blockDim.x + threadIdx.x;
    if (i >= N_NODES) return;
    float di = dinv[i], di2 = di * di;
    float x20 = agg2[i * 2]     + x2pre[i * 2]     * di2 + b2[0];
    float x21 = agg2[i * 2 + 1] + x2pre[i * 2 + 1] * di2 + b2[1];
    // outputs: [ sigmoid head (N) | x2 (N*2) ]
    out[N_NODES + i * 2]     = x20;
    out[N_NODES + i * 2 + 1] = x21;
    float r0 = x20 > 0.0f ? x20 : 0.0f;
    float r1 = x21 > 0.0f ? x21 : 0.0f;
    float z = r0 * lin_w[0] + r1 * lin_w[1] + lin_b[0];
    out[i] = 1.0f / (1.0f + expf(-z));
}

extern "C" void kernel_launch(void* const* d_in, const int* in_sizes, int n_in,
                              void* d_out, int out_size, void* d_ws, size_t ws_size,
                              hipStream_t stream) {
    const float* x     = (const float*)d_in[0];
    const int*   ei    = (const int*)d_in[1];   // [2, E] flattened
    const float* ew    = (const float*)d_in[2];
    const float* W1    = (const float*)d_in[3];
    const float* b1    = (const float*)d_in[4];
    const float* W2    = (const float*)d_in[5];
    const float* b2    = (const float*)d_in[6];
    const float* lin_w = (const float*)d_in[7];
    const float* lin_b = (const float*)d_in[8];
    float* out = (float*)d_out;

    const int* src = ei;
    const int* dst = ei + N_EDGES;

    float* ws    = (float*)d_ws;
    float* deg   = ws;
    float* dinv  = ws + (size_t)N_NODES;
    float* h1    = ws + (size_t)2 * N_NODES;
    float* agg1  = ws + (size_t)18 * N_NODES;
    float* h2    = ws + (size_t)34 * N_NODES;
    float* x2pre = ws + (size_t)50 * N_NODES;
    float* agg2  = ws + (size_t)52 * N_NODES;

    const int B = 256;
    // zero the scatter accumulators (ws is poisoned before each call)
    hipMemsetAsync(agg1, 0, (size_t)16 * N_NODES * sizeof(float), stream);
    hipMemsetAsync(agg2, 0, (size_t)2 * N_NODES * sizeof(float), stream);

    init_deg<<<(N_NODES + B - 1) / B, B, 0, stream>>>(deg);
    deg_accum<<<(N_EDGES + B - 1) / B, B, 0, stream>>>(dst, ew, deg);
    deg_rsqrt<<<(N_NODES + B - 1) / B, B, 0, stream>>>(deg, dinv);

    gemm1<<<(16 * N_NODES + B - 1) / B, B, 0, stream>>>(x, W1, h1);
    scatter1<<<(16 * N_EDGES + B - 1) / B, B, 0, stream>>>(src, dst, ew, dinv, h1, agg1);
    post1<<<(16 * N_NODES + B - 1) / B, B, 0, stream>>>(agg1, h1, dinv, b1, h2);

    gemm2<<<(N_NODES + B - 1) / B, B, 0, stream>>>(h2, W2, x2pre);
    scatter2<<<(2 * N_EDGES + B - 1) / B, B, 0, stream>>>(src, dst, ew, dinv, x2pre, agg2);
    final_k<<<(N_NODES + B - 1) / B, B, 0, stream>>>(agg2, x2pre, dinv, b2, lin_w, lin_b, out);
}